// Round 8
// baseline (190.922 us; speedup 1.0000x reference)
//
#include <hip/hip_runtime.h>

typedef __bf16 bf16_t;
typedef __bf16 bf16x8 __attribute__((ext_vector_type(8)));
typedef __bf16 bf16x4 __attribute__((ext_vector_type(4)));
typedef float f32x4 __attribute__((ext_vector_type(4)));

static __device__ __forceinline__ f32x4 mfma16(bf16x8 a, bf16x8 b, f32x4 c) {
    return __builtin_amdgcn_mfma_f32_16x16x32_bf16(a, b, c, 0, 0, 0);
}

#define AS1 __attribute__((address_space(1)))
#define AS3 __attribute__((address_space(3)))
static __device__ __forceinline__ void gload16(const void* g, void* l) {
    __builtin_amdgcn_global_load_lds((AS1 const void*)g, (AS3 void*)l, 16, 0, 0);
}

constexpr int B_ = 2, S_ = 2048, H_ = 16, DH = 128, AF = 2048;
constexpr int M_ = B_ * S_;  // 4096

// ---------------- f32 -> bf16 convert (query) ----------------
__global__ void cvt_f32_to_bf16(const float* __restrict__ in, bf16_t* __restrict__ out) {
    int i = (blockIdx.x * 256 + threadIdx.x) * 4;
    const float4 v = *reinterpret_cast<const float4*>(in + i);
    bf16x4 o = { (bf16_t)v.x, (bf16_t)v.y, (bf16_t)v.z, (bf16_t)v.w };
    *reinterpret_cast<bf16x4*>(out + i) = o;
}

// ---------------- f32 [R][C] -> bf16 [C][R] transpose ----------------
__global__ void transpose_to_bf16(const float* __restrict__ in, bf16_t* __restrict__ out,
                                  int R, int C) {
    __shared__ float t[32][33];
    int c0 = blockIdx.x * 32, r0 = blockIdx.y * 32;
    int tx = threadIdx.x & 31, ty = threadIdx.x >> 5;  // 32 x 8
#pragma unroll
    for (int i = 0; i < 4; i++) t[ty + i * 8][tx] = in[(size_t)(r0 + ty + i * 8) * C + c0 + tx];
    __syncthreads();
#pragma unroll
    for (int i = 0; i < 4; i++)
        out[(size_t)(c0 + ty + i * 8) * R + r0 + tx] = (bf16_t)t[tx][ty + i * 8];
}

// ---------------- Q+K fused GEMM: 256x256 tile, BK=32, triple-buffer, counted vmcnt ----
// C[m][n'] = A[4096x1024] @ WqkT[n'][k] (n' in [0,4096): Wq rows then Wk rows).
// 256 blocks = exactly one grid-wave. 8 waves (2Mx4N), per-wave 128x64 (acc[8][4]).
// LDS 96KB = 3 x (A 16KB + B 16KB). Pipeline: while computing K-tile k (buf k%3),
// stage K-tile k+2 (buf (k+2)%3, last read in body k-1); gate between tiles is
// s_waitcnt vmcnt(4) (k+1's 4 loads/thread may stay in flight) + raw s_barrier —
// NOT __syncthreads (which drains vmcnt(0), the m97 stall). T2-style chunk^row swizzle.
__global__ __launch_bounds__(512, 2) void qk256(
    const bf16_t* __restrict__ A, const bf16_t* __restrict__ Bt,
    const float* __restrict__ bq, const float* __restrict__ bk,
    bf16_t* __restrict__ C) {
    constexpr int NKT = 1024 / 32;
    __shared__ __align__(16) char L[98304];  // buf p: A @ p*32768, B @ +16384

    // bijective XCD swizzle: XCD x owns 2 adjacent 4x4 tile-clusters (L2: ~6MB/XCD)
    const int b0 = blockIdx.x;                       // 0..255
    const int l = (b0 & 7) * 32 + (b0 >> 3);
    const int cl = l >> 4, p = l & 15;
    const int mt = (cl >> 2) * 4 + (p >> 2), nt = (cl & 3) * 4 + (p & 3);
    const int m0 = mt * 256, n0 = nt * 256;
    const int tid = threadIdx.x, lane = tid & 63, wave = tid >> 6;
    const int wr = wave >> 2, wc = wave & 3;
    const int fr = lane & 15, fq = lane >> 4;

    f32x4 acc[8][4];
    const f32x4 fz = {0.f, 0.f, 0.f, 0.f};
#pragma unroll
    for (int i = 0; i < 8; ++i)
#pragma unroll
        for (int j = 0; j < 4; ++j) acc[i][j] = fz;

    auto stage = [&](int buf, int kt) {
        const int k0 = kt * 32;
#pragma unroll
        for (int i = 0; i < 2; ++i) {
            const int ch = tid + 512 * i;            // chunk 0..1023
            const int r = ch >> 2, cc = ch & 3;      // row 0..255, 16B chunk in 64B row
            const int sc = (cc ^ (r & 3)) << 3;      // pre-swizzled source col (elems)
            gload16(A + (size_t)(m0 + r) * 1024 + k0 + sc, L + buf * 32768 + ch * 16);
            gload16(Bt + (size_t)(n0 + r) * 1024 + k0 + sc, L + buf * 32768 + 16384 + ch * 16);
        }
    };

    stage(0, 0);
    stage(1, 1);
    asm volatile("s_waitcnt vmcnt(4)" ::: "memory");   // tile 0 landed; tile 1 in flight
    __builtin_amdgcn_s_barrier();

    for (int kt = 0; kt < NKT; ++kt) {
        if (kt + 2 < NKT) stage((kt + 2) % 3, kt + 2);
        const char* Ab = L + (kt % 3) * 32768;
        const char* Bb = Ab + 16384;
        bf16x8 af[8], bfv[4];
#pragma unroll
        for (int mi = 0; mi < 8; ++mi) {
            const int r = wr * 128 + mi * 16 + fr;
            af[mi] = *reinterpret_cast<const bf16x8*>(Ab + r * 64 + ((fq * 16) ^ ((r & 3) << 4)));
        }
#pragma unroll
        for (int ni = 0; ni < 4; ++ni) {
            const int r = wc * 64 + ni * 16 + fr;
            bfv[ni] = *reinterpret_cast<const bf16x8*>(Bb + r * 64 + ((fq * 16) ^ ((r & 3) << 4)));
        }
        __builtin_amdgcn_s_setprio(1);
#pragma unroll
        for (int mi = 0; mi < 8; ++mi)
#pragma unroll
            for (int ni = 0; ni < 4; ++ni)
                acc[mi][ni] = mfma16(af[mi], bfv[ni], acc[mi][ni]);
        __builtin_amdgcn_s_setprio(0);
        if (kt + 2 < NKT) {
            asm volatile("s_waitcnt vmcnt(4)" ::: "memory");  // k+1 done; k+2 in flight
        } else {
            asm volatile("s_waitcnt vmcnt(0)" ::: "memory");  // drain tail
        }
        __builtin_amdgcn_s_barrier();
    }

    // epilogue: col = n-side + fr, row = m-side + fq*4 + j (verified layout)
#pragma unroll
    for (int ni = 0; ni < 4; ++ni) {
        const int col = n0 + wc * 64 + ni * 16 + fr;
        const float bb = (col < 2048) ? bq[col] : bk[col - 2048];
        bf16_t* Cz = C + (size_t)(col >> 11) * ((size_t)M_ * 2048);
        const int c2 = col & 2047;
#pragma unroll
        for (int mi = 0; mi < 8; ++mi) {
            const int row = m0 + wr * 128 + mi * 16 + fq * 4;
            f32x4 v = acc[mi][ni];
#pragma unroll
            for (int j = 0; j < 4; ++j)
                Cz[(size_t)(row + j) * 2048 + c2] = (bf16_t)(v[j] + bb);
        }
    }
}

// ---------------- 128x128-tile bf16 GEMM: C = A[M][K] * Bt[N][K]^T + bias ----------------
// staging via global_load_lds width=16 (linear LDS dest, pre-swizzled source col).
template <int K, int N, bool OUTBF16, bool QKV, int ZOFF>
__global__ __launch_bounds__(256) void gemm128(
    const bf16_t* __restrict__ A, const bf16_t* __restrict__ Bt,
    const float* __restrict__ b0, const float* __restrict__ b1, const float* __restrict__ b2,
    bf16_t* __restrict__ Cqk, bf16_t* __restrict__ Vt, float* __restrict__ Cf) {
    __shared__ bf16_t As[128 * 64];
    __shared__ bf16_t Bs[128 * 64];
    const int z = blockIdx.z + ZOFF;
    const bf16_t* Bz = Bt + (size_t)z * N * K;
    const float* bias = (z == 0) ? b0 : (z == 1 ? b1 : b2);
    const int m0 = blockIdx.y * 128, n0 = blockIdx.x * 128;
    const int tid = threadIdx.x, lane = tid & 63, wave = tid >> 6;
    const int wm = (wave >> 1) * 64, wn = (wave & 1) * 64;
    const int fr = lane & 15, fq = lane >> 4;

    f32x4 acc[4][4];
    const f32x4 fz = {0.f, 0.f, 0.f, 0.f};
#pragma unroll
    for (int i = 0; i < 4; i++)
#pragma unroll
        for (int j = 0; j < 4; j++) acc[i][j] = fz;

    for (int kt = 0; kt < K / 64; ++kt) {
        const int k0 = kt * 64;
#pragma unroll
        for (int j = 0; j < 4; j++) {
            int cid = tid + 256 * j;
            int r = cid >> 3;
            int sc = ((cid & 7) ^ (r & 7)) << 3;
            gload16(A + (size_t)(m0 + r) * K + k0 + sc, (char*)As + cid * 16);
            gload16(Bz + (size_t)(n0 + r) * K + k0 + sc, (char*)Bs + cid * 16);
        }
        __syncthreads();
#pragma unroll
        for (int ks = 0; ks < 2; ++ks) {
            bf16x8 af[4], bfv[4];
#pragma unroll
            for (int mi = 0; mi < 4; mi++) {
                int r = wm + mi * 16 + fr;
                int cb = (ks * 64 + fq * 16) ^ ((r & 7) << 4);
                af[mi] = *reinterpret_cast<const bf16x8*>(reinterpret_cast<const char*>(As) + r * 128 + cb);
            }
#pragma unroll
            for (int ni = 0; ni < 4; ni++) {
                int r = wn + ni * 16 + fr;
                int cb = (ks * 64 + fq * 16) ^ ((r & 7) << 4);
                bfv[ni] = *reinterpret_cast<const bf16x8*>(reinterpret_cast<const char*>(Bs) + r * 128 + cb);
            }
            __builtin_amdgcn_s_setprio(1);
#pragma unroll
            for (int mi = 0; mi < 4; mi++)
#pragma unroll
                for (int ni = 0; ni < 4; ni++) acc[mi][ni] = mfma16(af[mi], bfv[ni], acc[mi][ni]);
            __builtin_amdgcn_s_setprio(0);
        }
        __syncthreads();
    }

#pragma unroll
    for (int ni = 0; ni < 4; ni++) {
        const int col = n0 + wn + ni * 16 + fr;
        const float bb = bias[col];
#pragma unroll
        for (int mi = 0; mi < 4; mi++) {
            const int mrow = m0 + wm + mi * 16 + fq * 4;
            f32x4 v = acc[mi][ni];
            if (OUTBF16) {
                if (QKV && z == 2) {
                    const int b = mrow >> 11, s = mrow & (S_ - 1);
                    const int h = col >> 7, d = col & (DH - 1);
                    bf16x4 w = { (bf16_t)(v[0] + bb), (bf16_t)(v[1] + bb),
                                 (bf16_t)(v[2] + bb), (bf16_t)(v[3] + bb) };
                    *reinterpret_cast<bf16x4*>(Vt + ((size_t)((b * H_ + h) * DH + d)) * S_ + s) = w;
                } else {
                    bf16_t* Cz = Cqk + (size_t)z * M_ * N;
#pragma unroll
                    for (int j = 0; j < 4; j++)
                        Cz[(size_t)(mrow + j) * N + col] = (bf16_t)(v[j] + bb);
                }
            } else {
#pragma unroll
                for (int j = 0; j < 4; j++) Cf[(size_t)(mrow + j) * N + col] = v[j] + bb;
            }
        }
    }
}

// ---------------- causal flash attention, v6 (unchanged from R7) ----------------
constexpr int TS_ = 16384;  // one 64x128 bf16 tile in LDS

__global__ __launch_bounds__(512, 2) void attn(
    const bf16_t* __restrict__ Q, const bf16_t* __restrict__ Kc,
    const bf16_t* __restrict__ Vt, bf16_t* __restrict__ Ctx) {
    const int id = blockIdx.x;
    const int bh = id & 31, b = bh >> 4, h = bh & 15;
    const int pr = id >> 5;
    const int lane = threadIdx.x & 63, wave = threadIdx.x >> 6;
    const int fr = lane & 15, fq = lane >> 4;
    const int qw = wave & 3, strm = wave >> 2;

    __shared__ __align__(16) char L[131072];

    const bf16_t* Kbase = Kc + (size_t)b * S_ * AF + h * DH;
    const bf16_t* Vbase = Vt + (size_t)bh * DH * S_;
    const float scale = 0.022097086912079608f;  // 1/sqrt(2048)
    const f32x4 fz = {0.f, 0.f, 0.f, 0.f};

    auto stage = [&](int p, int t0) {
#pragma unroll
        for (int i = 0; i < 2; ++i) {
            const int c = (int)threadIdx.x + 512 * i;
            const int r = c >> 4, cc = c & 15;
            gload16(Kbase + (size_t)(t0 * 64 + r) * AF + ((cc ^ (r & 7)) << 3),
                    L + (0 * 2 + p) * TS_ + c * 16);
            gload16(Kbase + (size_t)((t0 + 1) * 64 + r) * AF + ((cc ^ (r & 7)) << 3),
                    L + (1 * 2 + p) * TS_ + c * 16);
            const int rv = c >> 3, cv = c & 7;
            gload16(Vbase + (size_t)rv * S_ + t0 * 64 + ((cv ^ (rv & 7)) << 3),
                    L + 65536 + (0 * 2 + p) * TS_ + c * 16);
            gload16(Vbase + (size_t)rv * S_ + (t0 + 1) * 64 + ((cv ^ (rv & 7)) << 3),
                    L + 65536 + (1 * 2 + p) * TS_ + c * 16);
        }
    };

    for (int ph = 0; ph < 2; ++ph) {
        const int qt = ph ? (15 - pr) : pr;
        const int q0 = qt * 128;
        const int nst = qt + 1;

        bf16x8 qf[2][4];
#pragma unroll
        for (int qg = 0; qg < 2; ++qg) {
            const bf16_t* qp = Q + (size_t)(b * S_ + q0 + qw * 32 + qg * 16 + fr) * AF + h * DH + fq * 8;
#pragma unroll
            for (int ds = 0; ds < 4; ++ds) qf[qg][ds] = *reinterpret_cast<const bf16x8*>(qp + ds * 32);
        }
        float m_[2] = {-88.f, -88.f}, l_[2] = {0.f, 0.f};
        f32x4 o[2][8];
#pragma unroll
        for (int qg = 0; qg < 2; ++qg)
#pragma unroll
            for (int d = 0; d < 8; ++d) o[qg][d] = fz;

        __syncthreads();
        stage(0, 0);
        __syncthreads();

        for (int k = 0; k < nst; ++k) {
            if (k + 1 < nst) stage((k + 1) & 1, 2 * k + 2);
            const int ts = 2 * k + strm;
            const int kv0 = ts * 64;
            const char* kb = L + (strm * 2 + (k & 1)) * TS_;
            const char* vb = L + 65536 + (strm * 2 + (k & 1)) * TS_;

            f32x4 sv[2][4];
            __builtin_amdgcn_s_setprio(1);
#pragma unroll
            for (int kvf = 0; kvf < 4; ++kvf) {
                bf16x8 kf[4];
#pragma unroll
                for (int ds = 0; ds < 4; ++ds) {
                    const int r = kvf * 16 + fr;
                    kf[ds] = *reinterpret_cast<const bf16x8*>(kb + r * 256 + ((ds * 64 + fq * 16) ^ ((r & 7) << 4)));
                }
                sv[0][kvf] = fz; sv[1][kvf] = fz;
#pragma unroll
                for (int ds = 0; ds < 4; ++ds) {
                    sv[0][kvf] = mfma16(kf[ds], qf[0][ds], sv[0][kvf]);
                    sv[1][kvf] = mfma16(kf[ds], qf[1][ds], sv[1][kvf]);
                }
            }
            __builtin_amdgcn_s_setprio(0);
            const bool diag = (ts >= 2 * qt);

            uint32_t pk[2][8];
#pragma unroll
            for (int qg = 0; qg < 2; ++qg) {
                const int q_abs = q0 + qw * 32 + qg * 16 + fr;
                float x[16], mx = -3.0e38f;
#pragma unroll
                for (int kvf = 0; kvf < 4; ++kvf)
#pragma unroll
                    for (int r = 0; r < 4; ++r) {
                        float tv = sv[qg][kvf][r] * scale;
                        if (diag && (kv0 + kvf * 16 + fq * 4 + r > q_abs)) tv = -3.0e38f;
                        x[kvf * 4 + r] = tv;
                        mx = fmaxf(mx, tv);
                    }
                mx = fmaxf(mx, __shfl_xor(mx, 16, 64));
                mx = fmaxf(mx, __shfl_xor(mx, 32, 64));
                float mnew = m_[qg];
                if (!__all(mx <= m_[qg] + 8.f)) {
                    mnew = fmaxf(m_[qg], mx);
                    const float corr = __expf(m_[qg] - mnew);
                    l_[qg] *= corr;
                    float cr[4];
#pragma unroll
                    for (int r = 0; r < 4; ++r) cr[r] = __shfl(corr, fq * 4 + r, 64);
#pragma unroll
                    for (int d = 0; d < 8; ++d)
#pragma unroll
                        for (int r = 0; r < 4; ++r) o[qg][d][r] *= cr[r];
                    m_[qg] = mnew;
                }
                float rs = 0.f;
#pragma unroll
                for (int jj = 0; jj < 16; ++jj) { x[jj] = __expf(x[jj] - mnew); rs += x[jj]; }
                rs += __shfl_xor(rs, 16, 64);
                rs += __shfl_xor(rs, 32, 64);
                l_[qg] += rs;
#pragma unroll
                for (int j = 0; j < 8; ++j)
                    asm("v_cvt_pk_bf16_f32 %0, %1, %2" : "=v"(pk[qg][j]) : "v"(x[2 * j]), "v"(x[2 * j + 1]));
            }

#pragma unroll
            for (int ks = 0; ks < 2; ++ks) {
                bf16x8 pa[2];
#pragma unroll
                for (int qg = 0; qg < 2; ++qg) {
                    union { uint32_t w[4]; bf16x8 v; } u;
#pragma unroll
                    for (int w = 0; w < 4; ++w) {
                        const int sl = (fq & 1) * 32 + (w >> 1) * 16 + fr;
                        const int a0 = __shfl((int)pk[qg][ks * 4 + (w & 1)], sl, 64);
                        const int a1 = __shfl((int)pk[qg][ks * 4 + 2 + (w & 1)], sl, 64);
                        u.w[w] = (uint32_t)((fq >> 1) ? a1 : a0);
                    }
                    pa[qg] = u.v;
                }
                __builtin_amdgcn_s_setprio(1);
#pragma unroll
                for (int d = 0; d < 8; ++d) {
                    const int rv = d * 16 + fr;
                    const bf16x8 vf = *reinterpret_cast<const bf16x8*>(
                        vb + rv * 128 + ((ks * 64 + fq * 16) ^ ((rv & 7) << 4)));
                    o[0][d] = mfma16(pa[0], vf, o[0][d]);
                    o[1][d] = mfma16(pa[1], vf, o[1][d]);
                }
                __builtin_amdgcn_s_setprio(0);
            }
            __syncthreads();
        }

        if (strm == 1) {
#pragma unroll
            for (int qg = 0; qg < 2; ++qg) {
#pragma unroll
                for (int d = 0; d < 8; ++d)
                    *reinterpret_cast<f32x4*>(L + qw * 16384 + (qg * 8 + d) * 1024 + lane * 16) = o[qg][d];
                float2 ml = { m_[qg], l_[qg] };
                *reinterpret_cast<float2*>(L + 65536 + ((qw * 2 + qg) * 64 + lane) * 8) = ml;
            }
        }
        __syncthreads();
        if (strm == 0) {
#pragma unroll
            for (int qg = 0; qg < 2; ++qg) {
                float c0[4], c1[4], li[4];
#pragma unroll
                for (int r = 0; r < 4; ++r) {
                    const float2 ml1 = *reinterpret_cast<const float2*>(
                        L + 65536 + ((qw * 2 + qg) * 64 + (fq * 4 + r)) * 8);
                    const float m0r = __shfl(m_[qg], fq * 4 + r, 64);
                    const float l0r = __shfl(l_[qg], fq * 4 + r, 64);
                    const float mm = fmaxf(m0r, ml1.x);
                    c0[r] = __expf(m0r - mm);
                    c1[r] = __expf(ml1.x - mm);
                    li[r] = 1.0f / (l0r * c0[r] + ml1.y * c1[r]);
                }
#pragma unroll
                for (int d = 0; d < 8; ++d) {
                    const f32x4 o1 = *reinterpret_cast<const f32x4*>(
                        L + qw * 16384 + (qg * 8 + d) * 1024 + lane * 16);
#pragma unroll
                    for (int r = 0; r < 4; ++r) {
                        const size_t row = (size_t)(b * S_ + q0 + qw * 32 + qg * 16 + fq * 4 + r);
                        Ctx[row * AF + h * DH + d * 16 + fr] =
                            (bf16_t)((o[qg][d][r] * c0[r] + o1[r] * c1[r]) * li[r]);
                    }
                }
            }
        }
        __syncthreads();
    }
}

extern "C" void kernel_launch(void* const* d_in, const int* in_sizes, int n_in,
                              void* d_out, int out_size, void* d_ws, size_t ws_size,
                              hipStream_t stream) {
    const float* query = (const float*)d_in[0];
    const float* Wq = (const float*)d_in[1];
    const float* bq = (const float*)d_in[2];
    const float* Wk = (const float*)d_in[3];
    const float* bk = (const float*)d_in[4];
    const float* Wv = (const float*)d_in[5];
    const float* bv = (const float*)d_in[6];
    const float* Wo = (const float*)d_in[7];
    const float* bo = (const float*)d_in[8];
    float* out = (float*)d_out;
    char* ws = (char*)d_ws;

    bf16_t* xbf  = (bf16_t*)(ws + 0);
    bf16_t* wtq  = (bf16_t*)(ws + 8388608);   // [3][2048][1024] (Wq^T, Wk^T, Wv^T)
    bf16_t* wto  = (bf16_t*)(ws + 20971520);
    bf16_t* qws  = (bf16_t*)(ws + 25165824);  // Q [4096][2048], then K at +4096*2048
    bf16_t* vtws = (bf16_t*)(ws + 58720256);
    bf16_t* ctx  = (bf16_t*)(ws + 0);

    cvt_f32_to_bf16<<<4096, 256, 0, stream>>>(query, xbf);
    transpose_to_bf16<<<dim3(64, 32), 256, 0, stream>>>(Wq, wtq, 1024, 2048);
    transpose_to_bf16<<<dim3(64, 32), 256, 0, stream>>>(Wk, wtq + 2097152, 1024, 2048);
    transpose_to_bf16<<<dim3(64, 32), 256, 0, stream>>>(Wv, wtq + 2 * 2097152, 1024, 2048);
    transpose_to_bf16<<<dim3(32, 64), 256, 0, stream>>>(Wo, wto, 2048, 1024);

    // Q+K: fused N=4096 GEMM, 256 blocks (one perfect grid-wave)
    qk256<<<256, 512, 0, stream>>>(xbf, wtq, bq, bk, qws);
    // V: verified 128^2 path with transposed-Vt epilogue (z fixed to 2 via ZOFF)
    gemm128<1024, 2048, true, true, 2><<<dim3(16, 32, 1), 256, 0, stream>>>(
        xbf, wtq, bq, bk, bv, qws, vtws, nullptr);

    attn<<<256, 512, 0, stream>>>(qws, qws + (size_t)4096 * 2048, vtws, ctx);

    gemm128<2048, 1024, false, false, 0><<<dim3(8, 32, 1), 256, 0, stream>>>(
        ctx, wto, bo, bo, bo, nullptr, nullptr, out);
}

// Round 10
// 181.505 us; speedup vs baseline: 1.0519x; 1.0519x over previous
//
#include <hip/hip_runtime.h>

typedef __bf16 bf16_t;
typedef __bf16 bf16x8 __attribute__((ext_vector_type(8)));
typedef __bf16 bf16x4 __attribute__((ext_vector_type(4)));
typedef float f32x4 __attribute__((ext_vector_type(4)));

static __device__ __forceinline__ f32x4 mfma16(bf16x8 a, bf16x8 b, f32x4 c) {
    return __builtin_amdgcn_mfma_f32_16x16x32_bf16(a, b, c, 0, 0, 0);
}
static __device__ __forceinline__ float exp2v(float x) {
    float r; asm("v_exp_f32 %0, %1" : "=v"(r) : "v"(x)); return r;
}

#define AS1 __attribute__((address_space(1)))
#define AS3 __attribute__((address_space(3)))
static __device__ __forceinline__ void gload16(const void* g, void* l) {
    __builtin_amdgcn_global_load_lds((AS1 const void*)g, (AS3 void*)l, 16, 0, 0);
}

constexpr int B_ = 2, S_ = 2048, H_ = 16, DH = 128, AF = 2048;
constexpr int M_ = B_ * S_;  // 4096

// ---------------- f32 -> bf16 convert (query) ----------------
__global__ void cvt_f32_to_bf16(const float* __restrict__ in, bf16_t* __restrict__ out) {
    int i = (blockIdx.x * 256 + threadIdx.x) * 4;
    const float4 v = *reinterpret_cast<const float4*>(in + i);
    bf16x4 o = { (bf16_t)v.x, (bf16_t)v.y, (bf16_t)v.z, (bf16_t)v.w };
    *reinterpret_cast<bf16x4*>(out + i) = o;
}

// ---------------- f32 [R][C] -> bf16 [C][R] transpose ----------------
__global__ void transpose_to_bf16(const float* __restrict__ in, bf16_t* __restrict__ out,
                                  int R, int C) {
    __shared__ float t[32][33];
    int c0 = blockIdx.x * 32, r0 = blockIdx.y * 32;
    int tx = threadIdx.x & 31, ty = threadIdx.x >> 5;  // 32 x 8
#pragma unroll
    for (int i = 0; i < 4; i++) t[ty + i * 8][tx] = in[(size_t)(r0 + ty + i * 8) * C + c0 + tx];
    __syncthreads();
#pragma unroll
    for (int i = 0; i < 4; i++)
        out[(size_t)(c0 + ty + i * 8) * R + r0 + tx] = (bf16_t)t[tx][ty + i * 8];
}

// ---------------- 128x128-tile bf16 GEMM: C = A[M][K] * Bt[N][K]^T + bias ----------------
// staging via global_load_lds width=16 (linear LDS dest, pre-swizzled source col).
template <int K, int N, bool OUTBF16, bool QKV>
__global__ __launch_bounds__(256) void gemm128(
    const bf16_t* __restrict__ A, const bf16_t* __restrict__ Bt,
    const float* __restrict__ b0, const float* __restrict__ b1, const float* __restrict__ b2,
    bf16_t* __restrict__ Cqk, bf16_t* __restrict__ Vt, float* __restrict__ Cf) {
    __shared__ bf16_t As[128 * 64];
    __shared__ bf16_t Bs[128 * 64];
    const int z = blockIdx.z;
    const bf16_t* Bz = Bt + (size_t)z * N * K;
    const float* bias = (z == 0) ? b0 : (z == 1 ? b1 : b2);
    const int m0 = blockIdx.y * 128, n0 = blockIdx.x * 128;
    const int tid = threadIdx.x, lane = tid & 63, wave = tid >> 6;
    const int wm = (wave >> 1) * 64, wn = (wave & 1) * 64;
    const int fr = lane & 15, fq = lane >> 4;

    f32x4 acc[4][4];
    const f32x4 fz = {0.f, 0.f, 0.f, 0.f};
#pragma unroll
    for (int i = 0; i < 4; i++)
#pragma unroll
        for (int j = 0; j < 4; j++) acc[i][j] = fz;

    for (int kt = 0; kt < K / 64; ++kt) {
        const int k0 = kt * 64;
#pragma unroll
        for (int j = 0; j < 4; j++) {
            int cid = tid + 256 * j;
            int r = cid >> 3;
            int sc = ((cid & 7) ^ (r & 7)) << 3;
            gload16(A + (size_t)(m0 + r) * K + k0 + sc, (char*)As + cid * 16);
            gload16(Bz + (size_t)(n0 + r) * K + k0 + sc, (char*)Bs + cid * 16);
        }
        __syncthreads();
#pragma unroll
        for (int ks = 0; ks < 2; ++ks) {
            bf16x8 af[4], bfv[4];
#pragma unroll
            for (int mi = 0; mi < 4; mi++) {
                int r = wm + mi * 16 + fr;
                int cb = (ks * 64 + fq * 16) ^ ((r & 7) << 4);
                af[mi] = *reinterpret_cast<const bf16x8*>(reinterpret_cast<const char*>(As) + r * 128 + cb);
            }
#pragma unroll
            for (int ni = 0; ni < 4; ni++) {
                int r = wn + ni * 16 + fr;
                int cb = (ks * 64 + fq * 16) ^ ((r & 7) << 4);
                bfv[ni] = *reinterpret_cast<const bf16x8*>(reinterpret_cast<const char*>(Bs) + r * 128 + cb);
            }
            __builtin_amdgcn_s_setprio(1);
#pragma unroll
            for (int mi = 0; mi < 4; mi++)
#pragma unroll
                for (int ni = 0; ni < 4; ni++) acc[mi][ni] = mfma16(af[mi], bfv[ni], acc[mi][ni]);
            __builtin_amdgcn_s_setprio(0);
        }
        __syncthreads();
    }

#pragma unroll
    for (int ni = 0; ni < 4; ni++) {
        const int col = n0 + wn + ni * 16 + fr;
        const float bb = bias[col];
#pragma unroll
        for (int mi = 0; mi < 4; mi++) {
            const int mrow = m0 + wm + mi * 16 + fq * 4;
            f32x4 v = acc[mi][ni];
            if (OUTBF16) {
                if (QKV && z == 2) {
                    const int b = mrow >> 11, s = mrow & (S_ - 1);
                    const int h = col >> 7, d = col & (DH - 1);
                    bf16x4 w = { (bf16_t)(v[0] + bb), (bf16_t)(v[1] + bb),
                                 (bf16_t)(v[2] + bb), (bf16_t)(v[3] + bb) };
                    *reinterpret_cast<bf16x4*>(Vt + ((size_t)((b * H_ + h) * DH + d)) * S_ + s) = w;
                } else {
                    bf16_t* Cz = Cqk + (size_t)z * M_ * N;
#pragma unroll
                    for (int j = 0; j < 4; j++)
                        Cz[(size_t)(mrow + j) * N + col] = (bf16_t)(v[j] + bb);
                }
            } else {
#pragma unroll
                for (int j = 0; j < 4; j++) Cf[(size_t)(mrow + j) * N + col] = v[j] + bb;
            }
        }
    }
}

// ---------------- causal flash attention, v7.1 ----------------
// v7.1 = v7 with the PV shuffle FIXED: __shfl evaluates its value arg on the SOURCE
// lane, so register indices must be lane-uniform; the (fq>>1)-dependent word choice
// is a post-shuffle SELECT (v6's verified pattern), not an index into pk.
// Swapped PV: O^T = mfma(V-rows, P-rows) -> D[row=d][col=q=fr]; m/l/corr lane-local,
// epilogue has no cross-lane ops and stores packed bf16x4 along d.
// Softmax in log2 domain (scale2 = scale*log2e, v_exp_f32 = 2^x), THR 11.54 = 8*log2e.
constexpr int TS_ = 16384;  // one 64x128 bf16 tile in LDS

__global__ __launch_bounds__(512, 2) void attn(
    const bf16_t* __restrict__ Q, const bf16_t* __restrict__ Kc,
    const bf16_t* __restrict__ Vt, bf16_t* __restrict__ Ctx) {
    const int id = blockIdx.x;
    const int bh = id & 31, b = bh >> 4, h = bh & 15;
    const int pr = id >> 5;
    const int lane = threadIdx.x & 63, wave = threadIdx.x >> 6;
    const int fr = lane & 15, fq = lane >> 4;
    const int qw = wave & 3, strm = wave >> 2;

    __shared__ __align__(16) char L[131072];  // K bufs [s][p] @ (s*2+p)*TS_, V @ 65536+...

    const bf16_t* Kbase = Kc + (size_t)b * S_ * AF + h * DH;
    const bf16_t* Vbase = Vt + (size_t)bh * DH * S_;
    const float scale2 = 0.0318793617f;  // 1/sqrt(2048) * log2(e)
    const f32x4 fz = {0.f, 0.f, 0.f, 0.f};

    auto stage = [&](int p, int t0) {
#pragma unroll
        for (int i = 0; i < 2; ++i) {
            const int c = (int)threadIdx.x + 512 * i;
            const int r = c >> 4, cc = c & 15;
            gload16(Kbase + (size_t)(t0 * 64 + r) * AF + ((cc ^ (r & 7)) << 3),
                    L + (0 * 2 + p) * TS_ + c * 16);
            gload16(Kbase + (size_t)((t0 + 1) * 64 + r) * AF + ((cc ^ (r & 7)) << 3),
                    L + (1 * 2 + p) * TS_ + c * 16);
            const int rv = c >> 3, cv = c & 7;
            gload16(Vbase + (size_t)rv * S_ + t0 * 64 + ((cv ^ (rv & 7)) << 3),
                    L + 65536 + (0 * 2 + p) * TS_ + c * 16);
            gload16(Vbase + (size_t)rv * S_ + (t0 + 1) * 64 + ((cv ^ (rv & 7)) << 3),
                    L + 65536 + (1 * 2 + p) * TS_ + c * 16);
        }
    };

    for (int ph = 0; ph < 2; ++ph) {
        const int qt = ph ? (15 - pr) : pr;
        const int q0 = qt * 128;
        const int nst = qt + 1;

        bf16x8 qf[2][4];
#pragma unroll
        for (int qg = 0; qg < 2; ++qg) {
            const bf16_t* qp = Q + (size_t)(b * S_ + q0 + qw * 32 + qg * 16 + fr) * AF + h * DH + fq * 8;
#pragma unroll
            for (int ds = 0; ds < 4; ++ds) qf[qg][ds] = *reinterpret_cast<const bf16x8*>(qp + ds * 32);
        }
        float m_[2] = {-126.f, -126.f}, l_[2] = {0.f, 0.f};  // log2 domain
        f32x4 o[2][8];   // o[qg][df][r] = O[d = df*16+fq*4+r][q = own row fr]
#pragma unroll
        for (int qg = 0; qg < 2; ++qg)
#pragma unroll
            for (int d = 0; d < 8; ++d) o[qg][d] = fz;

        __syncthreads();
        stage(0, 0);
        __syncthreads();

        for (int k = 0; k < nst; ++k) {
            if (k + 1 < nst) stage((k + 1) & 1, 2 * k + 2);
            const int ts = 2 * k + strm;
            const int kv0 = ts * 64;
            const char* kb = L + (strm * 2 + (k & 1)) * TS_;
            const char* vb = L + 65536 + (strm * 2 + (k & 1)) * TS_;

            // ---- QK^T (swapped): sv[qg][kvf][r] = S[kv=kvf*16+fq*4+r][q=fr] ----
            f32x4 sv[2][4];
            __builtin_amdgcn_s_setprio(1);
#pragma unroll
            for (int kvf = 0; kvf < 4; ++kvf) {
                bf16x8 kf[4];
#pragma unroll
                for (int ds = 0; ds < 4; ++ds) {
                    const int r = kvf * 16 + fr;
                    kf[ds] = *reinterpret_cast<const bf16x8*>(kb + r * 256 + ((ds * 64 + fq * 16) ^ ((r & 7) << 4)));
                }
                sv[0][kvf] = fz; sv[1][kvf] = fz;
#pragma unroll
                for (int ds = 0; ds < 4; ++ds) {
                    sv[0][kvf] = mfma16(kf[ds], qf[0][ds], sv[0][kvf]);
                    sv[1][kvf] = mfma16(kf[ds], qf[1][ds], sv[1][kvf]);
                }
            }
            __builtin_amdgcn_s_setprio(0);
            const bool diag = (ts >= 2 * qt);

            // ---- softmax per qg (log2 domain); P packed to bf16 pairs in registers ----
            uint32_t pk[2][8];
#pragma unroll
            for (int qg = 0; qg < 2; ++qg) {
                const int q_abs = q0 + qw * 32 + qg * 16 + fr;
                float x[16], mx = -3.0e38f;
#pragma unroll
                for (int kvf = 0; kvf < 4; ++kvf)
#pragma unroll
                    for (int r = 0; r < 4; ++r) {
                        float tv = sv[qg][kvf][r] * scale2;
                        if (diag && (kv0 + kvf * 16 + fq * 4 + r > q_abs)) tv = -3.0e38f;
                        x[kvf * 4 + r] = tv;
                        mx = fmaxf(mx, tv);
                    }
                mx = fmaxf(mx, __shfl_xor(mx, 16, 64));
                mx = fmaxf(mx, __shfl_xor(mx, 32, 64));
                float mnew = m_[qg];
                if (!__all(mx <= m_[qg] + 11.54f)) {   // defer-max (T13), log2 units
                    mnew = fmaxf(m_[qg], mx);
                    const float corr = exp2v(m_[qg] - mnew);   // lane-local
                    l_[qg] *= corr;
#pragma unroll
                    for (int d = 0; d < 8; ++d)
#pragma unroll
                        for (int r = 0; r < 4; ++r) o[qg][d][r] *= corr;
                    m_[qg] = mnew;
                }
                float rs = 0.f;
#pragma unroll
                for (int jj = 0; jj < 16; ++jj) { x[jj] = exp2v(x[jj] - mnew); rs += x[jj]; }
                rs += __shfl_xor(rs, 16, 64);
                rs += __shfl_xor(rs, 32, 64);
                l_[qg] += rs;
#pragma unroll
                for (int j = 0; j < 8; ++j)
                    asm("v_cvt_pk_bf16_f32 %0, %1, %2" : "=v"(pk[qg][j]) : "v"(x[2 * j]), "v"(x[2 * j + 1]));
            }

            // ---- swapped PV: o[qg][df] = mfma(V-rows, P-rows) ----
            // dest lane (fr,fq), word w needs P[kv=ks*32+fq*8+2w+e][q=fr]:
            //   src lane = ((fq&1)*2 + (w>>1))*16 + fr   (lane-uniform shfl index per w)
            //   src word = ks*4 + (fq>>1)*2 + (w&1)      -> shfl BOTH, select on fq>>1
#pragma unroll
            for (int ks = 0; ks < 2; ++ks) {
                const int sl0 = ((fq & 1) * 2) * 16 + fr;
                bf16x8 pb[2];
#pragma unroll
                for (int qg = 0; qg < 2; ++qg) {
                    union { uint32_t w[4]; bf16x8 v; } u;
#pragma unroll
                    for (int w = 0; w < 4; ++w) {
                        const int sl = sl0 + (w >> 1) * 16;
                        const int a0 = __shfl((int)pk[qg][ks * 4 + (w & 1)], sl, 64);
                        const int a1 = __shfl((int)pk[qg][ks * 4 + 2 + (w & 1)], sl, 64);
                        u.w[w] = (uint32_t)((fq >> 1) ? a1 : a0);
                    }
                    pb[qg] = u.v;
                }
                __builtin_amdgcn_s_setprio(1);
#pragma unroll
                for (int df = 0; df < 8; ++df) {
                    const int rv = df * 16 + fr;
                    const bf16x8 av = *reinterpret_cast<const bf16x8*>(
                        vb + rv * 128 + ((ks * 64 + fq * 16) ^ ((rv & 7) << 4)));
                    o[0][df] = mfma16(av, pb[0], o[0][df]);
                    o[1][df] = mfma16(av, pb[1], o[1][df]);
                }
                __builtin_amdgcn_s_setprio(0);
            }
            __syncthreads();
        }

        // ---- stream merge + epilogue (all per-lane: q = q0+qw*32+qg*16+fr) ----
        if (strm == 1) {
#pragma unroll
            for (int qg = 0; qg < 2; ++qg) {
#pragma unroll
                for (int df = 0; df < 8; ++df)
                    *reinterpret_cast<f32x4*>(L + qw * 16384 + (qg * 8 + df) * 1024 + lane * 16) = o[qg][df];
                float2 ml = { m_[qg], l_[qg] };
                *reinterpret_cast<float2*>(L + 65536 + ((qw * 2 + qg) * 64 + lane) * 8) = ml;
            }
        }
        __syncthreads();
        if (strm == 0) {
#pragma unroll
            for (int qg = 0; qg < 2; ++qg) {
                const float2 ml1 = *reinterpret_cast<const float2*>(
                    L + 65536 + ((qw * 2 + qg) * 64 + lane) * 8);
                const float mm = fmaxf(m_[qg], ml1.x);
                const float c0 = exp2v(m_[qg] - mm);
                const float c1 = exp2v(ml1.x - mm);
                const float li = 1.0f / (l_[qg] * c0 + ml1.y * c1);
                const size_t row = (size_t)(b * S_ + q0 + qw * 32 + qg * 16 + fr);
#pragma unroll
                for (int df = 0; df < 8; ++df) {
                    const f32x4 o1 = *reinterpret_cast<const f32x4*>(
                        L + qw * 16384 + (qg * 8 + df) * 1024 + lane * 16);
                    bf16x4 w;
#pragma unroll
                    for (int r = 0; r < 4; ++r)
                        w[r] = (bf16_t)((o[qg][df][r] * c0 + o1[r] * c1) * li);
                    *reinterpret_cast<bf16x4*>(Ctx + row * AF + h * DH + df * 16 + fq * 4) = w;
                }
            }
        }
        __syncthreads();
    }
}

extern "C" void kernel_launch(void* const* d_in, const int* in_sizes, int n_in,
                              void* d_out, int out_size, void* d_ws, size_t ws_size,
                              hipStream_t stream) {
    const float* query = (const float*)d_in[0];
    const float* Wq = (const float*)d_in[1];
    const float* bq = (const float*)d_in[2];
    const float* Wk = (const float*)d_in[3];
    const float* bk = (const float*)d_in[4];
    const float* Wv = (const float*)d_in[5];
    const float* bv = (const float*)d_in[6];
    const float* Wo = (const float*)d_in[7];
    const float* bo = (const float*)d_in[8];
    float* out = (float*)d_out;
    char* ws = (char*)d_ws;

    bf16_t* xbf  = (bf16_t*)(ws + 0);
    bf16_t* wtq  = (bf16_t*)(ws + 8388608);
    bf16_t* wto  = (bf16_t*)(ws + 20971520);
    bf16_t* qws  = (bf16_t*)(ws + 25165824);
    bf16_t* vtws = (bf16_t*)(ws + 58720256);
    bf16_t* ctx  = (bf16_t*)(ws + 0);

    cvt_f32_to_bf16<<<4096, 256, 0, stream>>>(query, xbf);
    transpose_to_bf16<<<dim3(64, 32), 256, 0, stream>>>(Wq, wtq, 1024, 2048);
    transpose_to_bf16<<<dim3(64, 32), 256, 0, stream>>>(Wk, wtq + 2097152, 1024, 2048);
    transpose_to_bf16<<<dim3(64, 32), 256, 0, stream>>>(Wv, wtq + 2 * 2097152, 1024, 2048);
    transpose_to_bf16<<<dim3(32, 64), 256, 0, stream>>>(Wo, wto, 2048, 1024);

    gemm128<1024, 2048, true, true><<<dim3(16, 32, 3), 256, 0, stream>>>(
        xbf, wtq, bq, bk, bv, qws, vtws, nullptr);

    attn<<<256, 512, 0, stream>>>(qws, qws + (size_t)4096 * 2048, vtws, ctx);

    gemm128<2048, 1024, false, false><<<dim3(8, 32, 1), 256, 0, stream>>>(
        ctx, wto, bo, bo, bo, nullptr, nullptr, out);
}